// Round 1
// baseline (962.404 us; speedup 1.0000x reference)
//
#include <hip/hip_runtime.h>
#include <math.h>

#define D_MODEL 1024
#define N_HEADS 16
#define N_PHASE 128
#define HEAD_DIM 64
#define B_SZ 2
#define L_SEQ 2048
#define QK_SCALE 0.35355339059327373f   // 1/sqrt(8)
#define LN_EPS 1e-5f
#define POS_COEF 0.07195578415606394f   // ln(10000)/128

// ---------------------------------------------------------------- helpers
__device__ __forceinline__ float wave_reduce_max(float v) {
#pragma unroll
  for (int off = 32; off > 0; off >>= 1) v = fmaxf(v, __shfl_xor(v, off));
  return v;
}
__device__ __forceinline__ float wave_reduce_sum(float v) {
#pragma unroll
  for (int off = 32; off > 0; off >>= 1) v += __shfl_xor(v, off);
  return v;
}
__device__ __forceinline__ float lane_bcast(float v, int lane) {
  return __uint_as_float(__builtin_amdgcn_readlane(__float_as_uint(v), lane));
}

// ---------------------------------------------------------------- GEMM
// C = A(M,K) @ B(N,K)^T, 64x64 tile, BK=16, 256 threads, 4x4 per thread.
// MODE 0: phase epilogue -> qf/kf (B,H,L,16) cos|sin, scaled by fscale
// MODE 1: V epilogue -> (B,H,L,64) head-major
// MODE 2: residual add -> row-major (M,N)
template <int MODE>
__global__ __launch_bounds__(256) void gemm_kernel(
    const float* __restrict__ A, const float* __restrict__ Bm,
    const float* __restrict__ bias, const float* __restrict__ resid,
    float* __restrict__ C, int M, int N, int K, float fscale) {
  __shared__ float As[64][17];
  __shared__ float Bs[64][17];
  const int tid = threadIdx.x;
  const int mBase = blockIdx.x * 64, nBase = blockIdx.y * 64;
  const int tx = tid & 15, ty = tid >> 4;
  const int lrow = tid >> 2, lseg = tid & 3;

  float acc[4][4];
#pragma unroll
  for (int i = 0; i < 4; ++i)
#pragma unroll
    for (int j = 0; j < 4; ++j) acc[i][j] = 0.f;

  for (int k0 = 0; k0 < K; k0 += 16) {
    __syncthreads();
    float4 av = *(const float4*)(A + (size_t)(mBase + lrow) * K + k0 + lseg * 4);
    float4 bv = *(const float4*)(Bm + (size_t)(nBase + lrow) * K + k0 + lseg * 4);
    As[lrow][lseg * 4 + 0] = av.x;
    As[lrow][lseg * 4 + 1] = av.y;
    As[lrow][lseg * 4 + 2] = av.z;
    As[lrow][lseg * 4 + 3] = av.w;
    Bs[lrow][lseg * 4 + 0] = bv.x;
    Bs[lrow][lseg * 4 + 1] = bv.y;
    Bs[lrow][lseg * 4 + 2] = bv.z;
    Bs[lrow][lseg * 4 + 3] = bv.w;
    __syncthreads();
#pragma unroll
    for (int kk = 0; kk < 16; ++kk) {
      float a[4], b[4];
#pragma unroll
      for (int i = 0; i < 4; ++i) a[i] = As[ty * 4 + i][kk];
#pragma unroll
      for (int j = 0; j < 4; ++j) b[j] = Bs[tx * 4 + j][kk];
#pragma unroll
      for (int i = 0; i < 4; ++i)
#pragma unroll
        for (int j = 0; j < 4; ++j) acc[i][j] = fmaf(a[i], b[j], acc[i][j]);
    }
  }

#pragma unroll
  for (int i = 0; i < 4; ++i) {
#pragma unroll
    for (int j = 0; j < 4; ++j) {
      const int m = mBase + ty * 4 + i;
      const int n = nBase + tx * 4 + j;
      float v = acc[i][j];
      if (MODE == 0) {
        const int l = m & (L_SEQ - 1);
        const int b = m >> 11;
        const float inv_freq = expf(-(float)(n & ~1) * POS_COEF);
        const float ang = v + bias[n] + (float)l * inv_freq;
        const int h = n >> 3, p = n & 7;
        const size_t base = ((size_t)((b << 4) + h) * L_SEQ + l) * 16;
        C[base + p] = cosf(ang) * fscale;
        C[base + 8 + p] = sinf(ang) * fscale;
      } else if (MODE == 1) {
        const int l = m & (L_SEQ - 1);
        const int b = m >> 11;
        const int h = n >> 6, d = n & 63;
        C[(((size_t)((b << 4) + h) * L_SEQ + l) << 6) + d] = v;
      } else {
        C[(size_t)m * N + n] = v + resid[(size_t)m * N + n];
      }
    }
  }
}

// ---------------------------------------------------------------- attention
// grid: (B*H, L/32). 256 threads = 4 waves; wave w owns rows qbase+w*8 .. +7.
// lane d owns output dim d (HEAD_DIM == 64 == wave size).
#define QROWS 32
#define KTILE 64
__global__ __launch_bounds__(256) void attn_kernel(
    const float* __restrict__ qf, const float* __restrict__ kf,
    const float* __restrict__ V, float* __restrict__ attn_out) {
  const int bh = blockIdx.x;
  const int qbase = blockIdx.y * QROWS;
  const int tid = threadIdx.x;
  const int w = tid >> 6, lane = tid & 63;

  __shared__ float q_s[QROWS][16];
  __shared__ float kf_s[16][65];  // transposed, padded
  __shared__ float v_s[KTILE][64];

  const float* qf_h = qf + (size_t)bh * (L_SEQ * 16);
  const float* kf_h = kf + (size_t)bh * (L_SEQ * 16);
  const float* V_h = V + (size_t)bh * (size_t)L_SEQ * 64;

  if (tid < QROWS * 16 / 4)
    ((float4*)q_s)[tid] = ((const float4*)(qf_h + (size_t)qbase * 16))[tid];

  float m_i[8], l_i[8], acc[8];
#pragma unroll
  for (int r = 0; r < 8; ++r) {
    m_i[r] = -INFINITY;
    l_i[r] = 0.f;
    acc[r] = 0.f;
  }

  const int ntiles = ((qbase + QROWS - 1) >> 6) + 1;
  for (int t = 0; t < ntiles; ++t) {
    const int j0 = t * KTILE;
    __syncthreads();
    // stage kf transposed
#pragma unroll
    for (int e = 0; e < 4; ++e) {
      const int idx = tid + e * 256;
      const int j = idx >> 4, p = idx & 15;
      kf_s[p][j] = kf_h[(size_t)j0 * 16 + idx];
    }
    // stage V tile
#pragma unroll
    for (int e = 0; e < 4; ++e) {
      const int idx = tid + e * 256;
      ((float4*)v_s)[idx] = ((const float4*)(V_h + (size_t)j0 * 64))[idx];
    }
    __syncthreads();

    float kreg[16];
#pragma unroll
    for (int p = 0; p < 16; ++p) kreg[p] = kf_s[p][lane];

    float wgt[8];
#pragma unroll
    for (int r = 0; r < 8; ++r) {
      const int i = qbase + w * 8 + r;
      if (j0 > i) {
        wgt[r] = 0.f;
        continue;
      }
      float s = -INFINITY;
      if (j0 + lane <= i) {
        float d = 0.f;
#pragma unroll
        for (int p = 0; p < 16; ++p) d = fmaf(q_s[w * 8 + r][p], kreg[p], d);
        s = d;
      }
      const float mt = wave_reduce_max(s);
      const float m_new = fmaxf(m_i[r], mt);
      const float alpha = __expf(m_i[r] - m_new);
      const float wv = __expf(s - m_new);
      const float rowsum = wave_reduce_sum(wv);
      l_i[r] = l_i[r] * alpha + rowsum;
      acc[r] *= alpha;
      m_i[r] = m_new;
      wgt[r] = wv;
    }

#pragma unroll
    for (int tt = 0; tt < KTILE; ++tt) {
      const float v = v_s[tt][lane];
#pragma unroll
      for (int r = 0; r < 8; ++r)
        acc[r] = fmaf(lane_bcast(wgt[r], tt), v, acc[r]);
    }
  }

  const int b = bh >> 4, h = bh & 15;
#pragma unroll
  for (int r = 0; r < 8; ++r) {
    const int i = qbase + w * 8 + r;
    const float inv = 1.0f / l_i[r];
    attn_out[((size_t)(b * L_SEQ + i)) * D_MODEL + h * HEAD_DIM + lane] =
        acc[r] * inv;
  }
}

// ---------------------------------------------------------------- layernorm (in place)
__global__ __launch_bounds__(256) void ln_kernel(float* __restrict__ io,
                                                 const float* __restrict__ gamma,
                                                 const float* __restrict__ beta) {
  const int row = blockIdx.x;
  float* p = io + (size_t)row * D_MODEL;
  const int tid = threadIdx.x;
  float4 x = ((const float4*)p)[tid];
  float s = x.x + x.y + x.z + x.w;
  float sq = x.x * x.x + x.y * x.y + x.z * x.z + x.w * x.w;
  s = wave_reduce_sum(s);
  sq = wave_reduce_sum(sq);
  __shared__ float ss[4], ssq[4];
  const int w = tid >> 6, lane = tid & 63;
  if (lane == 0) {
    ss[w] = s;
    ssq[w] = sq;
  }
  __syncthreads();
  s = ss[0] + ss[1] + ss[2] + ss[3];
  sq = ssq[0] + ssq[1] + ssq[2] + ssq[3];
  const float mean = s * (1.f / D_MODEL);
  const float var = sq * (1.f / D_MODEL) - mean * mean;
  const float rstd = rsqrtf(var + LN_EPS);
  const float4 g = ((const float4*)gamma)[tid];
  const float4 bt = ((const float4*)beta)[tid];
  float4 y;
  y.x = (x.x - mean) * rstd * g.x + bt.x;
  y.y = (x.y - mean) * rstd * g.y + bt.y;
  y.z = (x.z - mean) * rstd * g.z + bt.z;
  y.w = (x.w - mean) * rstd * g.w + bt.w;
  ((float4*)p)[tid] = y;
}

// ---------------------------------------------------------------- launch
extern "C" void kernel_launch(void* const* d_in, const int* in_sizes, int n_in,
                              void* d_out, int out_size, void* d_ws,
                              size_t ws_size, hipStream_t stream) {
  const float* x_real = (const float*)d_in[0];
  const float* x_imag = (const float*)d_in[1];
  const float* Wq = (const float*)d_in[2];
  const float* bq = (const float*)d_in[3];
  const float* Wk = (const float*)d_in[4];
  const float* bk = (const float*)d_in[5];
  const float* Wv = (const float*)d_in[6];
  const float* Wo = (const float*)d_in[7];
  const float* gamma = (const float*)d_in[8];
  const float* beta = (const float*)d_in[9];

  float* ws = (float*)d_ws;
  const size_t qf_sz = (size_t)B_SZ * N_HEADS * L_SEQ * 16;   // 1M floats
  const size_t v_sz = (size_t)B_SZ * N_HEADS * L_SEQ * 64;    // 4M floats
  float* qf = ws;
  float* kf = qf + qf_sz;
  float* Vh = kf + qf_sz;
  float* ao = Vh + v_sz;

  float* outr = (float*)d_out;
  float* outi = outr + (size_t)B_SZ * L_SEQ * D_MODEL;

  const dim3 blk(256);
  const int M = B_SZ * L_SEQ;  // 4096

  gemm_kernel<0><<<dim3(M / 64, N_PHASE / 64), blk, 0, stream>>>(
      x_imag, Wq, bq, nullptr, qf, M, N_PHASE, D_MODEL, QK_SCALE);
  gemm_kernel<0><<<dim3(M / 64, N_PHASE / 64), blk, 0, stream>>>(
      x_imag, Wk, bk, nullptr, kf, M, N_PHASE, D_MODEL, 1.0f);
  gemm_kernel<1><<<dim3(M / 64, D_MODEL / 64), blk, 0, stream>>>(
      x_real, Wv, nullptr, nullptr, Vh, M, D_MODEL, D_MODEL, 1.0f);
  attn_kernel<<<dim3(B_SZ * N_HEADS, L_SEQ / QROWS), blk, 0, stream>>>(qf, kf,
                                                                       Vh, ao);
  gemm_kernel<2><<<dim3(M / 64, D_MODEL / 64), blk, 0, stream>>>(
      ao, Wo, nullptr, x_real, outr, M, D_MODEL, D_MODEL, 1.0f);
  ln_kernel<<<dim3(M), blk, 0, stream>>>(outr, gamma, beta);
  hipMemcpyAsync(outi, x_imag, sizeof(float) * (size_t)B_SZ * L_SEQ * D_MODEL,
                 hipMemcpyDeviceToDevice, stream);
}

// Round 2
// 634.142 us; speedup vs baseline: 1.5176x; 1.5176x over previous
//
#include <hip/hip_runtime.h>
#include <math.h>

#define D_MODEL 1024
#define N_HEADS 16
#define N_PHASE 128
#define HEAD_DIM 64
#define B_SZ 2
#define L_SEQ 2048
#define QK_SCALE 0.35355339059327373f   // 1/sqrt(8)
#define LN_EPS 1e-5f
#define POS_COEF 0.07195578415606394f   // ln(10000)/128

typedef __attribute__((ext_vector_type(8))) short bf16x8;
typedef __attribute__((ext_vector_type(4))) float f32x4;

// ---------------------------------------------------------------- helpers
__device__ __forceinline__ float wave_reduce_sum(float v) {
#pragma unroll
  for (int off = 32; off > 0; off >>= 1) v += __shfl_xor(v, off);
  return v;
}
// f32 -> bf16 (RNE), dependency-free
__device__ __forceinline__ unsigned short f2bf(float x) {
  unsigned u = __float_as_uint(x);
  u += 0x7fffu + ((u >> 16) & 1u);
  return (unsigned short)(u >> 16);
}

// ---------------------------------------------------------------- GEMM (f32 VALU)
// C = A(M,K) @ B(N,K)^T, 64x64 tile, BK=16, 256 threads, 4x4 per thread.
// MODE 0: phase epilogue -> qf/kf (B,H,L,16) cos|sin  (bf16 out)
// MODE 1: V epilogue -> (B,H,L,64) head-major         (bf16 out)
// MODE 2: residual add -> row-major (M,N)             (f32 out)
template <int MODE>
__global__ __launch_bounds__(256) void gemm_kernel(
    const float* __restrict__ A, const float* __restrict__ Bm,
    const float* __restrict__ bias, const float* __restrict__ resid,
    float* __restrict__ C, int M, int N, int K, float fscale) {
  __shared__ float As[64][17];
  __shared__ float Bs[64][17];
  const int tid = threadIdx.x;
  const int mBase = blockIdx.x * 64, nBase = blockIdx.y * 64;
  const int tx = tid & 15, ty = tid >> 4;
  const int lrow = tid >> 2, lseg = tid & 3;

  float acc[4][4];
#pragma unroll
  for (int i = 0; i < 4; ++i)
#pragma unroll
    for (int j = 0; j < 4; ++j) acc[i][j] = 0.f;

  for (int k0 = 0; k0 < K; k0 += 16) {
    __syncthreads();
    float4 av = *(const float4*)(A + (size_t)(mBase + lrow) * K + k0 + lseg * 4);
    float4 bv = *(const float4*)(Bm + (size_t)(nBase + lrow) * K + k0 + lseg * 4);
    As[lrow][lseg * 4 + 0] = av.x;
    As[lrow][lseg * 4 + 1] = av.y;
    As[lrow][lseg * 4 + 2] = av.z;
    As[lrow][lseg * 4 + 3] = av.w;
    Bs[lrow][lseg * 4 + 0] = bv.x;
    Bs[lrow][lseg * 4 + 1] = bv.y;
    Bs[lrow][lseg * 4 + 2] = bv.z;
    Bs[lrow][lseg * 4 + 3] = bv.w;
    __syncthreads();
#pragma unroll
    for (int kk = 0; kk < 16; ++kk) {
      float a[4], b[4];
#pragma unroll
      for (int i = 0; i < 4; ++i) a[i] = As[ty * 4 + i][kk];
#pragma unroll
      for (int j = 0; j < 4; ++j) b[j] = Bs[tx * 4 + j][kk];
#pragma unroll
      for (int i = 0; i < 4; ++i)
#pragma unroll
        for (int j = 0; j < 4; ++j) acc[i][j] = fmaf(a[i], b[j], acc[i][j]);
    }
  }

  short* Cs = (short*)C;
#pragma unroll
  for (int i = 0; i < 4; ++i) {
#pragma unroll
    for (int j = 0; j < 4; ++j) {
      const int m = mBase + ty * 4 + i;
      const int n = nBase + tx * 4 + j;
      float v = acc[i][j];
      if (MODE == 0) {
        const int l = m & (L_SEQ - 1);
        const int b = m >> 11;
        const float inv_freq = expf(-(float)(n & ~1) * POS_COEF);
        const float ang = v + bias[n] + (float)l * inv_freq;
        const int h = n >> 3, p = n & 7;
        const size_t base = ((size_t)((b << 4) + h) * L_SEQ + l) * 16;
        Cs[base + p] = (short)f2bf(cosf(ang) * fscale);
        Cs[base + 8 + p] = (short)f2bf(sinf(ang) * fscale);
      } else if (MODE == 1) {
        const int l = m & (L_SEQ - 1);
        const int b = m >> 11;
        const int h = n >> 6, d = n & 63;
        Cs[(((size_t)((b << 4) + h) * L_SEQ + l) << 6) + d] = (short)f2bf(v);
      } else {
        C[(size_t)m * N + n] = v + resid[(size_t)m * N + n];
      }
    }
  }
}

// ---------------------------------------------------------------- V transpose
// V (BH, L, 64) bf16 -> Vt (BH, 64, L) bf16, via 64x64 LDS tile
__global__ __launch_bounds__(256) void vtrans_kernel(const short* __restrict__ V,
                                                     short* __restrict__ Vt) {
  const int bh = blockIdx.x;
  const int j0 = blockIdx.y * 64;
  __shared__ short tile[64][72];
  const int tid = threadIdx.x;
  const int r = tid >> 2, cseg = (tid & 3) * 16;

  const short* src = V + ((size_t)bh * L_SEQ + j0 + r) * 64 + cseg;
  *(bf16x8*)&tile[r][cseg] = *(const bf16x8*)src;
  *(bf16x8*)&tile[r][cseg + 8] = *(const bf16x8*)(src + 8);
  __syncthreads();

  bf16x8 o0, o1;
#pragma unroll
  for (int e = 0; e < 8; ++e) {
    o0[e] = tile[cseg + e][r];
    o1[e] = tile[cseg + 8 + e][r];
  }
  short* dst = Vt + ((size_t)bh * 64 + r) * L_SEQ + j0 + cseg;
  *(bf16x8*)dst = o0;
  *(bf16x8*)(dst + 8) = o1;
}

// ---------------------------------------------------------------- MFMA attention
// grid (B*H, L/64), 256 thr = 4 waves; wave w owns q rows qbase+w*16 .. +15.
// Swapped QK: S^T = mfma(Kf, Qf) -> lane owns q = lane&15, 4 j's per reg.
// PV: O^T = mfma(Vt-frag, P^T-frag) accumulated over j.
__global__ __launch_bounds__(256) void attn_mfma_kernel(
    const short* __restrict__ qf, const short* __restrict__ kf,
    const short* __restrict__ Vt, float* __restrict__ ao) {
  const int bh = blockIdx.x;
  const int qbase = blockIdx.y * 64;
  const int tid = threadIdx.x;
  const int w = tid >> 6;
  const int lane = tid & 63;
  const int g = lane >> 4;     // 16-lane group
  const int q16 = lane & 15;   // this lane's q row (within wave tile)
  const int qglob = qbase + w * 16 + q16;

  __shared__ short p_lds[4][16][72];  // per-wave P repack buffer

  const short* qf_h = qf + (size_t)bh * L_SEQ * 16;
  const short* kf_h = kf + (size_t)bh * L_SEQ * 16;
  const short* Vt_h = Vt + (size_t)bh * 64 * L_SEQ;

  // Q fragment (B-operand): B[k=feat][col=q], lane holds feats g*8..g*8+7.
  // Real features are 0..15 -> groups 2,3 hold zeros (K padded 16->32).
  bf16x8 qfrag = {0, 0, 0, 0, 0, 0, 0, 0};
  if (g < 2) qfrag = *(const bf16x8*)(qf_h + (size_t)qglob * 16 + g * 8);

  f32x4 o[4];
#pragma unroll
  for (int dc = 0; dc < 4; ++dc) o[dc] = (f32x4){0.f, 0.f, 0.f, 0.f};
  float m = -INFINITY, l = 0.f;

  const int ntiles = (qbase >> 6) + 1;
  for (int t = 0; t < ntiles; ++t) {
    const int j0 = t << 6;

    // ---- QK^T (swapped): 4 j-tiles of 16
    f32x4 s[4];
#pragma unroll
    for (int jt = 0; jt < 4; ++jt) {
      bf16x8 kfrag = {0, 0, 0, 0, 0, 0, 0, 0};
      if (g < 2)
        kfrag = *(const bf16x8*)(kf_h + (size_t)(j0 + jt * 16 + q16) * 16 + g * 8);
      s[jt] = __builtin_amdgcn_mfma_f32_16x16x32_bf16(
          kfrag, qfrag, (f32x4){0.f, 0.f, 0.f, 0.f}, 0, 0, 0);
    }

    // ---- causal mask (only the diagonal block needs it)
    if (t == ntiles - 1) {
#pragma unroll
      for (int jt = 0; jt < 4; ++jt)
#pragma unroll
        for (int r = 0; r < 4; ++r)
          if (j0 + jt * 16 + g * 4 + r > qglob) s[jt][r] = -INFINITY;
    }

    // ---- online softmax
    float tm = -INFINITY;
#pragma unroll
    for (int jt = 0; jt < 4; ++jt)
#pragma unroll
      for (int r = 0; r < 4; ++r) tm = fmaxf(tm, s[jt][r]);
    tm = fmaxf(tm, __shfl_xor(tm, 16));
    tm = fmaxf(tm, __shfl_xor(tm, 32));
    const float m_new = fmaxf(m, tm);
    const float alpha = __expf(m - m_new);
    float rs = 0.f;
#pragma unroll
    for (int jt = 0; jt < 4; ++jt)
#pragma unroll
      for (int r = 0; r < 4; ++r) {
        s[jt][r] = __expf(s[jt][r] - m_new);
        rs += s[jt][r];
      }
    rs += __shfl_xor(rs, 16);
    rs += __shfl_xor(rs, 32);
    l = l * alpha + rs;
    m = m_new;
#pragma unroll
    for (int dc = 0; dc < 4; ++dc) o[dc] *= alpha;

    // ---- P -> bf16 -> LDS (layout [q][j], row stride 72)
#pragma unroll
    for (int jt = 0; jt < 4; ++jt) {
      unsigned u0 = (unsigned)f2bf(s[jt][0]) | ((unsigned)f2bf(s[jt][1]) << 16);
      unsigned u1 = (unsigned)f2bf(s[jt][2]) | ((unsigned)f2bf(s[jt][3]) << 16);
      uint2 pk;
      pk.x = u0;
      pk.y = u1;
      *(uint2*)&p_lds[w][q16][jt * 16 + g * 4] = pk;
    }

    // ---- PV: O^T += V^T(16d x 32j) @ P^T(32j x 16q), 2 j-chunks x 4 d-chunks
#pragma unroll
    for (int c = 0; c < 2; ++c) {
      const bf16x8 pb = *(const bf16x8*)&p_lds[w][q16][c * 32 + g * 8];
#pragma unroll
      for (int dc = 0; dc < 4; ++dc) {
        const bf16x8 vfrag = *(const bf16x8*)(
            Vt_h + (size_t)(dc * 16 + q16) * L_SEQ + j0 + c * 32 + g * 8);
        o[dc] = __builtin_amdgcn_mfma_f32_16x16x32_bf16(vfrag, pb, o[dc], 0, 0, 0);
      }
    }
  }

  // ---- epilogue: O^T[d][q] / l -> ao (B,L,D_MODEL) f32
  const float inv = 1.f / l;
  const int b = bh >> 4, h = bh & 15;
  float* orow = ao + ((size_t)(b * L_SEQ + qglob)) * D_MODEL + h * 64;
#pragma unroll
  for (int dc = 0; dc < 4; ++dc)
#pragma unroll
    for (int r = 0; r < 4; ++r) orow[dc * 16 + g * 4 + r] = o[dc][r] * inv;
}

// ---------------------------------------------------------------- layernorm (in place)
__global__ __launch_bounds__(256) void ln_kernel(float* __restrict__ io,
                                                 const float* __restrict__ gamma,
                                                 const float* __restrict__ beta) {
  const int row = blockIdx.x;
  float* p = io + (size_t)row * D_MODEL;
  const int tid = threadIdx.x;
  float4 x = ((const float4*)p)[tid];
  float s = x.x + x.y + x.z + x.w;
  float sq = x.x * x.x + x.y * x.y + x.z * x.z + x.w * x.w;
  s = wave_reduce_sum(s);
  sq = wave_reduce_sum(sq);
  __shared__ float ss[4], ssq[4];
  const int w = tid >> 6, lane = tid & 63;
  if (lane == 0) {
    ss[w] = s;
    ssq[w] = sq;
  }
  __syncthreads();
  s = ss[0] + ss[1] + ss[2] + ss[3];
  sq = ssq[0] + ssq[1] + ssq[2] + ssq[3];
  const float mean = s * (1.f / D_MODEL);
  const float var = sq * (1.f / D_MODEL) - mean * mean;
  const float rstd = rsqrtf(var + LN_EPS);
  const float4 g = ((const float4*)gamma)[tid];
  const float4 bt = ((const float4*)beta)[tid];
  float4 y;
  y.x = (x.x - mean) * rstd * g.x + bt.x;
  y.y = (x.y - mean) * rstd * g.y + bt.y;
  y.z = (x.z - mean) * rstd * g.z + bt.z;
  y.w = (x.w - mean) * rstd * g.w + bt.w;
  ((float4*)p)[tid] = y;
}

// ---------------------------------------------------------------- launch
extern "C" void kernel_launch(void* const* d_in, const int* in_sizes, int n_in,
                              void* d_out, int out_size, void* d_ws,
                              size_t ws_size, hipStream_t stream) {
  const float* x_real = (const float*)d_in[0];
  const float* x_imag = (const float*)d_in[1];
  const float* Wq = (const float*)d_in[2];
  const float* bq = (const float*)d_in[3];
  const float* Wk = (const float*)d_in[4];
  const float* bk = (const float*)d_in[5];
  const float* Wv = (const float*)d_in[6];
  const float* Wo = (const float*)d_in[7];
  const float* gamma = (const float*)d_in[8];
  const float* beta = (const float*)d_in[9];

  const size_t qf_sz = (size_t)B_SZ * N_HEADS * L_SEQ * 16;  // 1M bf16
  const size_t v_sz = (size_t)B_SZ * N_HEADS * L_SEQ * 64;   // 4M bf16
  short* qf = (short*)d_ws;
  short* kf = qf + qf_sz;
  short* Vb = kf + qf_sz;
  short* Vt = Vb + v_sz;
  float* ao = (float*)(Vt + v_sz);

  float* outr = (float*)d_out;
  float* outi = outr + (size_t)B_SZ * L_SEQ * D_MODEL;

  const dim3 blk(256);
  const int M = B_SZ * L_SEQ;  // 4096

  gemm_kernel<0><<<dim3(M / 64, N_PHASE / 64), blk, 0, stream>>>(
      x_imag, Wq, bq, nullptr, (float*)qf, M, N_PHASE, D_MODEL, QK_SCALE);
  gemm_kernel<0><<<dim3(M / 64, N_PHASE / 64), blk, 0, stream>>>(
      x_imag, Wk, bk, nullptr, (float*)kf, M, N_PHASE, D_MODEL, 1.0f);
  gemm_kernel<1><<<dim3(M / 64, D_MODEL / 64), blk, 0, stream>>>(
      x_real, Wv, nullptr, nullptr, (float*)Vb, M, D_MODEL, D_MODEL, 1.0f);
  vtrans_kernel<<<dim3(B_SZ * N_HEADS, L_SEQ / 64), blk, 0, stream>>>(Vb, Vt);
  attn_mfma_kernel<<<dim3(B_SZ * N_HEADS, L_SEQ / 64), blk, 0, stream>>>(
      qf, kf, Vt, ao);
  gemm_kernel<2><<<dim3(M / 64, D_MODEL / 64), blk, 0, stream>>>(
      ao, Wo, nullptr, x_real, outr, M, D_MODEL, D_MODEL, 1.0f);
  ln_kernel<<<dim3(M), blk, 0, stream>>>(outr, gamma, beta);
  hipMemcpyAsync(outi, x_imag, sizeof(float) * (size_t)B_SZ * L_SEQ * D_MODEL,
                 hipMemcpyDeviceToDevice, stream);
}

// Round 3
// 375.324 us; speedup vs baseline: 2.5642x; 1.6896x over previous
//
#include <hip/hip_runtime.h>
#include <math.h>

#define D_MODEL 1024
#define N_HEADS 16
#define N_PHASE 128
#define HEAD_DIM 64
#define B_SZ 2
#define L_SEQ 2048
#define QK_SCALE 0.35355339059327373f   // 1/sqrt(8)
#define LN_EPS 1e-5f
#define POS_COEF 0.07195578415606394f   // ln(10000)/128

typedef __attribute__((ext_vector_type(8))) short bf16x8;
typedef __attribute__((ext_vector_type(4))) short s16x4;
typedef __attribute__((ext_vector_type(4))) float f32x4;

// ---------------------------------------------------------------- helpers
__device__ __forceinline__ float wave_reduce_sum(float v) {
#pragma unroll
  for (int off = 32; off > 0; off >>= 1) v += __shfl_xor(v, off);
  return v;
}
// f32 -> bf16 (RNE)
__device__ __forceinline__ unsigned short f2bf(float x) {
  unsigned u = __float_as_uint(x);
  u += 0x7fffu + ((u >> 16) & 1u);
  return (unsigned short)(u >> 16);
}
__device__ __forceinline__ void gload16(const short* g, short* l) {
  __builtin_amdgcn_global_load_lds(
      (const __attribute__((address_space(1))) void*)g,
      (__attribute__((address_space(3))) void*)l, 16, 0, 0);
}

// ---------------------------------------------------------------- f32 -> bf16 convert
__global__ __launch_bounds__(256) void cvt_kernel(const float* __restrict__ s,
                                                  short* __restrict__ d, int n4) {
  const int i = blockIdx.x * 256 + threadIdx.x;
  if (i < n4) {
    const float4 v = ((const float4*)s)[i];
    s16x4 o;
    o[0] = (short)f2bf(v.x);
    o[1] = (short)f2bf(v.y);
    o[2] = (short)f2bf(v.z);
    o[3] = (short)f2bf(v.w);
    ((s16x4*)d)[i] = o;
  }
}

// ---------------------------------------------------------------- MFMA GEMM
// C = A(M,K)bf16 @ B(N,K)bf16^T. 128x128 tile, BK=32, 4 waves (2x2), 4x4 frags.
// MODE 0: phase epilogue -> qf/kf (B,H,L,16) cos|sin bf16 (N==128, nBase==0)
// MODE 1: transposed V epilogue -> Vt (B,H,64,L) bf16
// MODE 2: residual add -> f32 row-major (M,N)
template <int MODE>
__global__ __launch_bounds__(256) void mgemm_kernel(
    const short* __restrict__ A, const short* __restrict__ Bm,
    const float* __restrict__ bias, const float* __restrict__ resid,
    void* __restrict__ Cp, int M, int N, int K, float fscale) {
  __shared__ short As[128 * 32];
  __shared__ short Bs[128 * 32];
  const int tid = threadIdx.x;
  const int wv = tid >> 6, ln = tid & 63;
  const int wr = wv >> 1, wc = wv & 1;
  const int fr = ln & 15, fc = ln >> 4;
  const int mBase = blockIdx.x * 128, nBase = blockIdx.y * 128;

  f32x4 acc[4][4];
#pragma unroll
  for (int i = 0; i < 4; ++i)
#pragma unroll
    for (int j = 0; j < 4; ++j) acc[i][j] = (f32x4){0.f, 0.f, 0.f, 0.f};

  // staging: wave wv covers 16 rows per issue; lane i -> row wv*16+i/4, 16B chunk i%4
  const short* ga = A + (size_t)(mBase + wv * 16 + (ln >> 2)) * K + (ln & 3) * 8;
  const short* gb = Bm + (size_t)(nBase + wv * 16 + (ln >> 2)) * K + (ln & 3) * 8;
  short* la = As + wv * 512;
  short* lb = Bs + wv * 512;

  for (int k0 = 0; k0 < K; k0 += 32) {
    __syncthreads();
    gload16(ga + k0, la);
    gload16(ga + k0 + (size_t)64 * K, la + 64 * 32);
    gload16(gb + k0, lb);
    gload16(gb + k0 + (size_t)64 * K, lb + 64 * 32);
    __syncthreads();

    bf16x8 af[4], bfr[4];
#pragma unroll
    for (int mi = 0; mi < 4; ++mi)
      af[mi] = *(const bf16x8*)&As[(wr * 64 + mi * 16 + fr) * 32 + fc * 8];
#pragma unroll
    for (int ni = 0; ni < 4; ++ni)
      bfr[ni] = *(const bf16x8*)&Bs[(wc * 64 + ni * 16 + fr) * 32 + fc * 8];

    if (MODE == 1) {
#pragma unroll
      for (int ni = 0; ni < 4; ++ni)
#pragma unroll
        for (int mi = 0; mi < 4; ++mi)
          acc[ni][mi] = __builtin_amdgcn_mfma_f32_16x16x32_bf16(
              bfr[ni], af[mi], acc[ni][mi], 0, 0, 0);
    } else {
#pragma unroll
      for (int mi = 0; mi < 4; ++mi)
#pragma unroll
        for (int ni = 0; ni < 4; ++ni)
          acc[mi][ni] = __builtin_amdgcn_mfma_f32_16x16x32_bf16(
              af[mi], bfr[ni], acc[mi][ni], 0, 0, 0);
    }
  }

  short* Cs = (short*)Cp;
  if (MODE == 0) {
#pragma unroll
    for (int mi = 0; mi < 4; ++mi)
#pragma unroll
      for (int ni = 0; ni < 4; ++ni)
#pragma unroll
        for (int r = 0; r < 4; ++r) {
          const int m = mBase + wr * 64 + mi * 16 + fc * 4 + r;
          const int n = wc * 64 + ni * 16 + fr;
          const int b = m >> 11, l = m & (L_SEQ - 1);
          const float inv_freq = expf(-(float)(n & ~1) * POS_COEF);
          const float ang = acc[mi][ni][r] + bias[n] + (float)l * inv_freq;
          const int h = n >> 3, p = n & 7;
          const size_t base = ((size_t)((b << 4) + h) * L_SEQ + l) * 16;
          Cs[base + p] = (short)f2bf(cosf(ang) * fscale);
          Cs[base + 8 + p] = (short)f2bf(sinf(ang) * fscale);
        }
  } else if (MODE == 1) {
#pragma unroll
    for (int ni = 0; ni < 4; ++ni)
#pragma unroll
      for (int mi = 0; mi < 4; ++mi)
#pragma unroll
        for (int r = 0; r < 4; ++r) {
          const int n = nBase + wc * 64 + ni * 16 + fc * 4 + r;
          const int m = mBase + wr * 64 + mi * 16 + fr;
          const int b = m >> 11, l = m & (L_SEQ - 1);
          const int h = n >> 6, d = n & 63;
          Cs[((size_t)((b << 4) + h) * 64 + d) * L_SEQ + l] =
              (short)f2bf(acc[ni][mi][r]);
        }
  } else {
    float* Cf = (float*)Cp;
#pragma unroll
    for (int mi = 0; mi < 4; ++mi)
#pragma unroll
      for (int ni = 0; ni < 4; ++ni)
#pragma unroll
        for (int r = 0; r < 4; ++r) {
          const int m = mBase + wr * 64 + mi * 16 + fc * 4 + r;
          const int n = nBase + wc * 64 + ni * 16 + fr;
          const size_t idx = (size_t)m * N + n;
          Cf[idx] = acc[mi][ni][r] + resid[idx];
        }
  }
}

// ---------------------------------------------------------------- MFMA attention
// grid (B*H, L/64), 256 thr = 4 waves; wave w owns q rows qbase+w*16 .. +15.
__global__ __launch_bounds__(256) void attn_mfma_kernel(
    const short* __restrict__ qf, const short* __restrict__ kf,
    const short* __restrict__ Vt, short* __restrict__ ao) {
  const int bh = blockIdx.x;
  const int qbase = blockIdx.y * 64;
  const int tid = threadIdx.x;
  const int w = tid >> 6;
  const int lane = tid & 63;
  const int g = lane >> 4;
  const int q16 = lane & 15;
  const int qglob = qbase + w * 16 + q16;

  __shared__ short p_lds[4][16][72];

  const short* qf_h = qf + (size_t)bh * L_SEQ * 16;
  const short* kf_h = kf + (size_t)bh * L_SEQ * 16;
  const short* Vt_h = Vt + (size_t)bh * 64 * L_SEQ;

  bf16x8 qfrag = {0, 0, 0, 0, 0, 0, 0, 0};
  if (g < 2) qfrag = *(const bf16x8*)(qf_h + (size_t)qglob * 16 + g * 8);

  f32x4 o[4];
#pragma unroll
  for (int dc = 0; dc < 4; ++dc) o[dc] = (f32x4){0.f, 0.f, 0.f, 0.f};
  float m = -INFINITY, l = 0.f;

  const int ntiles = (qbase >> 6) + 1;
  for (int t = 0; t < ntiles; ++t) {
    const int j0 = t << 6;

    f32x4 s[4];
#pragma unroll
    for (int jt = 0; jt < 4; ++jt) {
      bf16x8 kfrag = {0, 0, 0, 0, 0, 0, 0, 0};
      if (g < 2)
        kfrag = *(const bf16x8*)(kf_h + (size_t)(j0 + jt * 16 + q16) * 16 + g * 8);
      s[jt] = __builtin_amdgcn_mfma_f32_16x16x32_bf16(
          kfrag, qfrag, (f32x4){0.f, 0.f, 0.f, 0.f}, 0, 0, 0);
    }

    if (t == ntiles - 1) {
#pragma unroll
      for (int jt = 0; jt < 4; ++jt)
#pragma unroll
        for (int r = 0; r < 4; ++r)
          if (j0 + jt * 16 + g * 4 + r > qglob) s[jt][r] = -INFINITY;
    }

    float tm = -INFINITY;
#pragma unroll
    for (int jt = 0; jt < 4; ++jt)
#pragma unroll
      for (int r = 0; r < 4; ++r) tm = fmaxf(tm, s[jt][r]);
    tm = fmaxf(tm, __shfl_xor(tm, 16));
    tm = fmaxf(tm, __shfl_xor(tm, 32));
    const float m_new = fmaxf(m, tm);
    const float alpha = __expf(m - m_new);
    float rs = 0.f;
#pragma unroll
    for (int jt = 0; jt < 4; ++jt)
#pragma unroll
      for (int r = 0; r < 4; ++r) {
        s[jt][r] = __expf(s[jt][r] - m_new);
        rs += s[jt][r];
      }
    rs += __shfl_xor(rs, 16);
    rs += __shfl_xor(rs, 32);
    l = l * alpha + rs;
    m = m_new;
#pragma unroll
    for (int dc = 0; dc < 4; ++dc) o[dc] *= alpha;

#pragma unroll
    for (int jt = 0; jt < 4; ++jt) {
      uint2 pk;
      pk.x = (unsigned)f2bf(s[jt][0]) | ((unsigned)f2bf(s[jt][1]) << 16);
      pk.y = (unsigned)f2bf(s[jt][2]) | ((unsigned)f2bf(s[jt][3]) << 16);
      *(uint2*)&p_lds[w][q16][jt * 16 + g * 4] = pk;
    }

#pragma unroll
    for (int c = 0; c < 2; ++c) {
      const bf16x8 pb = *(const bf16x8*)&p_lds[w][q16][c * 32 + g * 8];
#pragma unroll
      for (int dc = 0; dc < 4; ++dc) {
        const bf16x8 vfrag = *(const bf16x8*)(
            Vt_h + (size_t)(dc * 16 + q16) * L_SEQ + j0 + c * 32 + g * 8);
        o[dc] = __builtin_amdgcn_mfma_f32_16x16x32_bf16(vfrag, pb, o[dc], 0, 0, 0);
      }
    }
  }

  const float inv = 1.f / l;
  const int b = bh >> 4, h = bh & 15;
  short* orow = ao + ((size_t)(b * L_SEQ + qglob)) * D_MODEL + h * 64;
#pragma unroll
  for (int dc = 0; dc < 4; ++dc)
#pragma unroll
    for (int r = 0; r < 4; ++r)
      orow[dc * 16 + g * 4 + r] = (short)f2bf(o[dc][r] * inv);
}

// ---------------------------------------------------------------- layernorm (in place)
__global__ __launch_bounds__(256) void ln_kernel(float* __restrict__ io,
                                                 const float* __restrict__ gamma,
                                                 const float* __restrict__ beta) {
  const int row = blockIdx.x;
  float* p = io + (size_t)row * D_MODEL;
  const int tid = threadIdx.x;
  float4 x = ((const float4*)p)[tid];
  float s = x.x + x.y + x.z + x.w;
  float sq = x.x * x.x + x.y * x.y + x.z * x.z + x.w * x.w;
  s = wave_reduce_sum(s);
  sq = wave_reduce_sum(sq);
  __shared__ float ss[4], ssq[4];
  const int w = tid >> 6, lane = tid & 63;
  if (lane == 0) {
    ss[w] = s;
    ssq[w] = sq;
  }
  __syncthreads();
  s = ss[0] + ss[1] + ss[2] + ss[3];
  sq = ssq[0] + ssq[1] + ssq[2] + ssq[3];
  const float mean = s * (1.f / D_MODEL);
  const float var = sq * (1.f / D_MODEL) - mean * mean;
  const float rstd = rsqrtf(var + LN_EPS);
  const float4 g = ((const float4*)gamma)[tid];
  const float4 bt = ((const float4*)beta)[tid];
  float4 y;
  y.x = (x.x - mean) * rstd * g.x + bt.x;
  y.y = (x.y - mean) * rstd * g.y + bt.y;
  y.z = (x.z - mean) * rstd * g.z + bt.z;
  y.w = (x.w - mean) * rstd * g.w + bt.w;
  ((float4*)p)[tid] = y;
}

// ---------------------------------------------------------------- launch
extern "C" void kernel_launch(void* const* d_in, const int* in_sizes, int n_in,
                              void* d_out, int out_size, void* d_ws,
                              size_t ws_size, hipStream_t stream) {
  const float* x_real = (const float*)d_in[0];
  const float* x_imag = (const float*)d_in[1];
  const float* Wq = (const float*)d_in[2];
  const float* bq = (const float*)d_in[3];
  const float* Wk = (const float*)d_in[4];
  const float* bk = (const float*)d_in[5];
  const float* Wv = (const float*)d_in[6];
  const float* Wo = (const float*)d_in[7];
  const float* gamma = (const float*)d_in[8];
  const float* beta = (const float*)d_in[9];

  const size_t n_x = (size_t)B_SZ * L_SEQ * D_MODEL;       // 4M
  const size_t n_w = (size_t)D_MODEL * D_MODEL;            // 1M
  const size_t n_wp = (size_t)N_PHASE * D_MODEL;           // 128K
  const size_t n_qf = (size_t)B_SZ * N_HEADS * L_SEQ * 16; // 1M

  short* xi_bf = (short*)d_ws;
  short* xr_bf = xi_bf + n_x;      // later reused as ao_bf
  short* Wq_bf = xr_bf + n_x;
  short* Wk_bf = Wq_bf + n_wp;
  short* Wv_bf = Wk_bf + n_wp;
  short* Wo_bf = Wv_bf + n_w;
  short* qf = Wo_bf + n_w;
  short* kf = qf + n_qf;
  short* Vt = kf + n_qf;           // 4M shorts
  short* ao_bf = xr_bf;            // alias: x_real bf16 dead after V GEMM

  float* outr = (float*)d_out;
  float* outi = outr + n_x;

  const dim3 blk(256);
  const int M = B_SZ * L_SEQ;  // 4096

  cvt_kernel<<<dim3((int)(n_x / 4 + 255) / 256), blk, 0, stream>>>(x_imag, xi_bf, n_x / 4);
  cvt_kernel<<<dim3((int)(n_x / 4 + 255) / 256), blk, 0, stream>>>(x_real, xr_bf, n_x / 4);
  cvt_kernel<<<dim3((int)(n_wp / 4 + 255) / 256), blk, 0, stream>>>(Wq, Wq_bf, n_wp / 4);
  cvt_kernel<<<dim3((int)(n_wp / 4 + 255) / 256), blk, 0, stream>>>(Wk, Wk_bf, n_wp / 4);
  cvt_kernel<<<dim3((int)(n_w / 4 + 255) / 256), blk, 0, stream>>>(Wv, Wv_bf, n_w / 4);
  cvt_kernel<<<dim3((int)(n_w / 4 + 255) / 256), blk, 0, stream>>>(Wo, Wo_bf, n_w / 4);

  mgemm_kernel<0><<<dim3(M / 128, 1), blk, 0, stream>>>(
      xi_bf, Wq_bf, bq, nullptr, qf, M, N_PHASE, D_MODEL, QK_SCALE);
  mgemm_kernel<0><<<dim3(M / 128, 1), blk, 0, stream>>>(
      xi_bf, Wk_bf, bk, nullptr, kf, M, N_PHASE, D_MODEL, 1.0f);
  mgemm_kernel<1><<<dim3(M / 128, D_MODEL / 128), blk, 0, stream>>>(
      xr_bf, Wv_bf, nullptr, nullptr, Vt, M, D_MODEL, D_MODEL, 1.0f);
  attn_mfma_kernel<<<dim3(B_SZ * N_HEADS, L_SEQ / 64), blk, 0, stream>>>(
      qf, kf, Vt, ao_bf);
  mgemm_kernel<2><<<dim3(M / 128, D_MODEL / 128), blk, 0, stream>>>(
      ao_bf, Wo_bf, nullptr, x_real, outr, M, D_MODEL, D_MODEL, 1.0f);
  ln_kernel<<<dim3(M), blk, 0, stream>>>(outr, gamma, beta);
  hipMemcpyAsync(outi, x_imag, sizeof(float) * n_x, hipMemcpyDeviceToDevice,
                 stream);
}

// Round 4
// 164.140 us; speedup vs baseline: 5.8633x; 2.2866x over previous
//
#include <hip/hip_runtime.h>
#include <math.h>

#define D_MODEL 1024
#define N_HEADS 16
#define N_PHASE 128
#define HEAD_DIM 64
#define B_SZ 2
#define L_SEQ 2048
#define QK_SCALE 0.35355339059327373f   // 1/sqrt(8)
#define LN_EPS 1e-5f
#define POS_COEF 0.07195578415606394f   // ln(10000)/128

typedef __attribute__((ext_vector_type(8))) short bf16x8;
typedef __attribute__((ext_vector_type(4))) short s16x4;
typedef __attribute__((ext_vector_type(4))) float f32x4;

// ---------------------------------------------------------------- helpers
__device__ __forceinline__ float wave_reduce_sum(float v) {
#pragma unroll
  for (int off = 32; off > 0; off >>= 1) v += __shfl_xor(v, off);
  return v;
}
// f32 -> bf16 (RNE)
__device__ __forceinline__ unsigned short f2bf(float x) {
  unsigned u = __float_as_uint(x);
  u += 0x7fffu + ((u >> 16) & 1u);
  return (unsigned short)(u >> 16);
}
__device__ __forceinline__ void gload16(const short* g, short* l) {
  __builtin_amdgcn_global_load_lds(
      (const __attribute__((address_space(1))) void*)g,
      (__attribute__((address_space(3))) void*)l, 16, 0, 0);
}

// ---------------------------------------------------------------- converts
__global__ __launch_bounds__(256) void cvt2_kernel(
    const float* __restrict__ s0, short* __restrict__ d0,
    const float* __restrict__ s1, short* __restrict__ d1, int n4) {
  const int i = blockIdx.x * 256 + threadIdx.x;
  if (i < n4) {
    float4 v = ((const float4*)s0)[i];
    s16x4 o;
    o[0] = (short)f2bf(v.x);
    o[1] = (short)f2bf(v.y);
    o[2] = (short)f2bf(v.z);
    o[3] = (short)f2bf(v.w);
    ((s16x4*)d0)[i] = o;
    v = ((const float4*)s1)[i];
    o[0] = (short)f2bf(v.x);
    o[1] = (short)f2bf(v.y);
    o[2] = (short)f2bf(v.z);
    o[3] = (short)f2bf(v.w);
    ((s16x4*)d1)[i] = o;
  }
}

// ---------------------------------------------------------------- GEMM core
// 128x64 tile, BK=32, 4 waves (2x2). Wave tile 64x32, frags af[4] x bfr[2].
// LDS chunk-XOR swizzle (involution c^((r>>1)&3)) applied on the GLOBAL source
// (gload_lds dest is linear) and on the LDS read side.
template <bool SWAP>
__device__ __forceinline__ void gemm_core(const short* __restrict__ A,
                                          const short* __restrict__ Bm, int K,
                                          int mBase, int nBase,
                                          f32x4 acc[4][2], short* As,
                                          short* Bs) {
  const int tid = threadIdx.x;
  const int wv = tid >> 6, ln = tid & 63;
  const int wr = wv >> 1, wc = wv & 1;
  const int fr = ln & 15, fc = ln >> 4;
  const int cg = (ln & 3) ^ ((ln >> 3) & 3);  // swizzled source chunk
  const short* ga = A + (size_t)(mBase + wv * 16 + (ln >> 2)) * K + cg * 8;
  const short* gb = Bm + (size_t)(nBase + wv * 16 + (ln >> 2)) * K + cg * 8;
  short* la = As + wv * 512;
  short* lb = Bs + wv * 512;
  const int ra = (wr * 64 + fr) * 32 + (fc ^ ((fr >> 1) & 3)) * 8;
  const int rb = (wc * 32 + fr) * 32 + (fc ^ ((fr >> 1) & 3)) * 8;

  for (int k0 = 0; k0 < K; k0 += 32) {
    __syncthreads();
    gload16(ga + k0, la);
    gload16(ga + k0 + (size_t)64 * K, la + 64 * 32);
    gload16(gb + k0, lb);
    __syncthreads();

    bf16x8 af[4], bfr[2];
#pragma unroll
    for (int mi = 0; mi < 4; ++mi) af[mi] = *(const bf16x8*)&As[ra + mi * 512];
#pragma unroll
    for (int ni = 0; ni < 2; ++ni) bfr[ni] = *(const bf16x8*)&Bs[rb + ni * 512];

#pragma unroll
    for (int mi = 0; mi < 4; ++mi)
#pragma unroll
      for (int ni = 0; ni < 2; ++ni)
        acc[mi][ni] = SWAP ? __builtin_amdgcn_mfma_f32_16x16x32_bf16(
                                 bfr[ni], af[mi], acc[mi][ni], 0, 0, 0)
                           : __builtin_amdgcn_mfma_f32_16x16x32_bf16(
                                 af[mi], bfr[ni], acc[mi][ni], 0, 0, 0);
  }
}

// ---------------------------------------------------------------- phase GEMM (Q & K fused)
__global__ __launch_bounds__(256) void pgemm_kernel(
    const short* __restrict__ A, const short* __restrict__ WqB,
    const short* __restrict__ WkB, const float* __restrict__ bq,
    const float* __restrict__ bk, short* __restrict__ qf,
    short* __restrict__ kf) {
  __shared__ short As[128 * 32];
  __shared__ short Bs[64 * 32];
  const int z = blockIdx.z;
  const short* Bm = z ? WkB : WqB;
  const float* bias = z ? bk : bq;
  short* Cs = z ? kf : qf;
  const float fscale = z ? 1.0f : QK_SCALE;
  const int mBase = blockIdx.x * 128, nBase = blockIdx.y * 64;

  f32x4 acc[4][2];
#pragma unroll
  for (int i = 0; i < 4; ++i)
#pragma unroll
    for (int j = 0; j < 2; ++j) acc[i][j] = (f32x4){0.f, 0.f, 0.f, 0.f};
  gemm_core<false>(A, Bm, D_MODEL, mBase, nBase, acc, As, Bs);

  const int ln = threadIdx.x & 63, wv = threadIdx.x >> 6;
  const int wr = wv >> 1, wc = wv & 1;
  const int fr = ln & 15, fc = ln >> 4;
#pragma unroll
  for (int mi = 0; mi < 4; ++mi)
#pragma unroll
    for (int ni = 0; ni < 2; ++ni)
#pragma unroll
      for (int r = 0; r < 4; ++r) {
        const int m = mBase + wr * 64 + mi * 16 + fc * 4 + r;
        const int n = nBase + wc * 32 + ni * 16 + fr;
        const int b = m >> 11, l = m & (L_SEQ - 1);
        const float inv_freq = expf(-(float)(n & ~1) * POS_COEF);
        const float ang = acc[mi][ni][r] + bias[n] + (float)l * inv_freq;
        const int h = n >> 3, p = n & 7;
        const size_t base = ((size_t)((b << 4) + h) * L_SEQ + l) * 16;
        Cs[base + p] = (short)f2bf(cosf(ang) * fscale);
        Cs[base + 8 + p] = (short)f2bf(sinf(ang) * fscale);
      }
}

// ---------------------------------------------------------------- V / O GEMMs
// MODE 1: transposed V epilogue -> Vt (B,H,64,L) bf16
// MODE 2: residual add -> f32 row-major (M, D_MODEL)
template <int MODE>
__global__ __launch_bounds__(256) void mgemm_kernel(
    const short* __restrict__ A, const short* __restrict__ Bm,
    const float* __restrict__ resid, void* __restrict__ Cp) {
  __shared__ short As[128 * 32];
  __shared__ short Bs[64 * 32];
  const int mBase = blockIdx.x * 128, nBase = blockIdx.y * 64;

  f32x4 acc[4][2];
#pragma unroll
  for (int i = 0; i < 4; ++i)
#pragma unroll
    for (int j = 0; j < 2; ++j) acc[i][j] = (f32x4){0.f, 0.f, 0.f, 0.f};
  gemm_core<MODE == 1>(A, Bm, D_MODEL, mBase, nBase, acc, As, Bs);

  const int ln = threadIdx.x & 63, wv = threadIdx.x >> 6;
  const int wr = wv >> 1, wc = wv & 1;
  const int fr = ln & 15, fc = ln >> 4;

  if (MODE == 1) {
    short* Cs = (short*)Cp;
#pragma unroll
    for (int mi = 0; mi < 4; ++mi)
#pragma unroll
      for (int ni = 0; ni < 2; ++ni)
#pragma unroll
        for (int r = 0; r < 4; ++r) {
          const int n = nBase + wc * 32 + ni * 16 + fc * 4 + r;
          const int m = mBase + wr * 64 + mi * 16 + fr;
          const int b = m >> 11, l = m & (L_SEQ - 1);
          const int h = n >> 6, d = n & 63;
          Cs[((size_t)((b << 4) + h) * 64 + d) * L_SEQ + l] =
              (short)f2bf(acc[mi][ni][r]);
        }
  } else {
    float* Cf = (float*)Cp;
#pragma unroll
    for (int mi = 0; mi < 4; ++mi)
#pragma unroll
      for (int ni = 0; ni < 2; ++ni)
#pragma unroll
        for (int r = 0; r < 4; ++r) {
          const int m = mBase + wr * 64 + mi * 16 + fc * 4 + r;
          const int n = nBase + wc * 32 + ni * 16 + fr;
          const size_t idx = (size_t)m * D_MODEL + n;
          Cf[idx] = acc[mi][ni][r] + resid[idx];
        }
  }
}

// ---------------------------------------------------------------- MFMA attention
// grid (B*H, L/64) with descending-y work order. 4 waves, wave w owns 16 q rows.
// Fixed-point softmax: scores bounded by 8*SCALE=2.83 -> exp(s) directly, no
// online max/rescale; per-lane lsum reduced once at the end.
__global__ __launch_bounds__(256) void attn_mfma_kernel(
    const short* __restrict__ qf, const short* __restrict__ kf,
    const short* __restrict__ Vt, short* __restrict__ ao) {
  const int bh = blockIdx.x;
  const int qbase = (gridDim.y - 1 - blockIdx.y) * 64;
  const int tid = threadIdx.x;
  const int w = tid >> 6;
  const int lane = tid & 63;
  const int g = lane >> 4;
  const int q16 = lane & 15;
  const int qglob = qbase + w * 16 + q16;

  __shared__ short p_lds[4][16][72];

  const short* qf_h = qf + (size_t)bh * L_SEQ * 16;
  const short* kf_h = kf + (size_t)bh * L_SEQ * 16;
  const short* Vt_h = Vt + (size_t)bh * 64 * L_SEQ;

  bf16x8 qfrag = {0, 0, 0, 0, 0, 0, 0, 0};
  if (g < 2) qfrag = *(const bf16x8*)(qf_h + (size_t)qglob * 16 + g * 8);

  f32x4 o[4];
#pragma unroll
  for (int dc = 0; dc < 4; ++dc) o[dc] = (f32x4){0.f, 0.f, 0.f, 0.f};
  float lsum = 0.f;

  const int ntiles = (qbase >> 6) + 1;

  bf16x8 kfr[4], kfn[4];
#pragma unroll
  for (int jt = 0; jt < 4; ++jt) {
    kfr[jt] = (bf16x8){0, 0, 0, 0, 0, 0, 0, 0};
    kfn[jt] = (bf16x8){0, 0, 0, 0, 0, 0, 0, 0};
  }
  if (g < 2) {
#pragma unroll
    for (int jt = 0; jt < 4; ++jt)
      kfr[jt] = *(const bf16x8*)(kf_h + (size_t)(jt * 16 + q16) * 16 + g * 8);
  }

  for (int t = 0; t < ntiles; ++t) {
    const int j0 = t << 6;

    // prefetch V (c=0 half) for this tile
    bf16x8 vf0[4];
#pragma unroll
    for (int dc = 0; dc < 4; ++dc)
      vf0[dc] = *(const bf16x8*)(Vt_h + (size_t)(dc * 16 + q16) * L_SEQ + j0 +
                                 g * 8);
    // prefetch K for next tile
    if (t + 1 < ntiles && g < 2) {
#pragma unroll
      for (int jt = 0; jt < 4; ++jt)
        kfn[jt] = *(const bf16x8*)(kf_h +
                                   (size_t)(j0 + 64 + jt * 16 + q16) * 16 +
                                   g * 8);
    }

    // QK^T (swapped): lane holds q=q16, j = j0 + jt*16 + g*4 + r
    f32x4 s[4];
#pragma unroll
    for (int jt = 0; jt < 4; ++jt)
      s[jt] = __builtin_amdgcn_mfma_f32_16x16x32_bf16(
          kfr[jt], qfrag, (f32x4){0.f, 0.f, 0.f, 0.f}, 0, 0, 0);

    // prefetch V (c=1 half)
    bf16x8 vf1[4];
#pragma unroll
    for (int dc = 0; dc < 4; ++dc)
      vf1[dc] = *(const bf16x8*)(Vt_h + (size_t)(dc * 16 + q16) * L_SEQ + j0 +
                                 32 + g * 8);

    // causal mask (diagonal tile only)
    if (t == ntiles - 1) {
#pragma unroll
      for (int jt = 0; jt < 4; ++jt)
#pragma unroll
        for (int r = 0; r < 4; ++r)
          if (j0 + jt * 16 + g * 4 + r > qglob) s[jt][r] = -INFINITY;
    }

    // exp + per-lane sum + pack to LDS
#pragma unroll
    for (int jt = 0; jt < 4; ++jt) {
      const float e0 = __expf(s[jt][0]);
      const float e1 = __expf(s[jt][1]);
      const float e2 = __expf(s[jt][2]);
      const float e3 = __expf(s[jt][3]);
      lsum += (e0 + e1) + (e2 + e3);
      uint2 pk;
      pk.x = (unsigned)f2bf(e0) | ((unsigned)f2bf(e1) << 16);
      pk.y = (unsigned)f2bf(e2) | ((unsigned)f2bf(e3) << 16);
      *(uint2*)&p_lds[w][q16][jt * 16 + g * 4] = pk;
    }

    // PV: O^T += V^T @ P^T
    {
      const bf16x8 pb0 = *(const bf16x8*)&p_lds[w][q16][g * 8];
#pragma unroll
      for (int dc = 0; dc < 4; ++dc)
        o[dc] = __builtin_amdgcn_mfma_f32_16x16x32_bf16(vf0[dc], pb0, o[dc], 0,
                                                        0, 0);
      const bf16x8 pb1 = *(const bf16x8*)&p_lds[w][q16][32 + g * 8];
#pragma unroll
      for (int dc = 0; dc < 4; ++dc)
        o[dc] = __builtin_amdgcn_mfma_f32_16x16x32_bf16(vf1[dc], pb1, o[dc], 0,
                                                        0, 0);
    }

#pragma unroll
    for (int jt = 0; jt < 4; ++jt) kfr[jt] = kfn[jt];
  }

  lsum += __shfl_xor(lsum, 16);
  lsum += __shfl_xor(lsum, 32);
  const float inv = 1.f / lsum;
  const int b = bh >> 4, h = bh & 15;
  short* orow = ao + ((size_t)(b * L_SEQ + qglob)) * D_MODEL + h * 64;
#pragma unroll
  for (int dc = 0; dc < 4; ++dc)
#pragma unroll
    for (int r = 0; r < 4; ++r)
      orow[dc * 16 + g * 4 + r] = (short)f2bf(o[dc][r] * inv);
}

// ---------------------------------------------------------------- layernorm (in place)
__global__ __launch_bounds__(256) void ln_kernel(float* __restrict__ io,
                                                 const float* __restrict__ gamma,
                                                 const float* __restrict__ beta) {
  const int row = blockIdx.x;
  float* p = io + (size_t)row * D_MODEL;
  const int tid = threadIdx.x;
  float4 x = ((const float4*)p)[tid];
  float s = x.x + x.y + x.z + x.w;
  float sq = x.x * x.x + x.y * x.y + x.z * x.z + x.w * x.w;
  s = wave_reduce_sum(s);
  sq = wave_reduce_sum(sq);
  __shared__ float ss[4], ssq[4];
  const int w = tid >> 6, lane = tid & 63;
  if (lane == 0) {
    ss[w] = s;
    ssq[w] = sq;
  }
  __syncthreads();
  s = ss[0] + ss[1] + ss[2] + ss[3];
  sq = ssq[0] + ssq[1] + ssq[2] + ssq[3];
  const float mean = s * (1.f / D_MODEL);
  const float var = sq * (1.f / D_MODEL) - mean * mean;
  const float rstd = rsqrtf(var + LN_EPS);
  const float4 g = ((const float4*)gamma)[tid];
  const float4 bt = ((const float4*)beta)[tid];
  float4 y;
  y.x = (x.x - mean) * rstd * g.x + bt.x;
  y.y = (x.y - mean) * rstd * g.y + bt.y;
  y.z = (x.z - mean) * rstd * g.z + bt.z;
  y.w = (x.w - mean) * rstd * g.w + bt.w;
  ((float4*)p)[tid] = y;
}

// ---------------------------------------------------------------- launch
extern "C" void kernel_launch(void* const* d_in, const int* in_sizes, int n_in,
                              void* d_out, int out_size, void* d_ws,
                              size_t ws_size, hipStream_t stream) {
  const float* x_real = (const float*)d_in[0];
  const float* x_imag = (const float*)d_in[1];
  const float* Wq = (const float*)d_in[2];
  const float* bq = (const float*)d_in[3];
  const float* Wk = (const float*)d_in[4];
  const float* bk = (const float*)d_in[5];
  const float* Wv = (const float*)d_in[6];
  const float* Wo = (const float*)d_in[7];
  const float* gamma = (const float*)d_in[8];
  const float* beta = (const float*)d_in[9];

  const size_t n_x = (size_t)B_SZ * L_SEQ * D_MODEL;        // 4M
  const size_t n_w = (size_t)D_MODEL * D_MODEL;             // 1M
  const size_t n_wp = (size_t)N_PHASE * D_MODEL;            // 128K
  const size_t n_qf = (size_t)B_SZ * N_HEADS * L_SEQ * 16;  // 1M

  short* xi_bf = (short*)d_ws;
  short* xr_bf = xi_bf + n_x;  // later reused as ao_bf
  short* Wq_bf = xr_bf + n_x;
  short* Wk_bf = Wq_bf + n_wp;
  short* Wv_bf = Wk_bf + n_wp;
  short* Wo_bf = Wv_bf + n_w;
  short* qf = Wo_bf + n_w;
  short* kf = qf + n_qf;
  short* Vt = kf + n_qf;  // 4M shorts
  short* ao_bf = xr_bf;   // alias: x_real bf16 dead after V GEMM

  float* outr = (float*)d_out;
  float* outi = outr + n_x;

  const dim3 blk(256);
  const int M = B_SZ * L_SEQ;  // 4096

  cvt2_kernel<<<dim3((int)(n_x / 4 / 256)), blk, 0, stream>>>(
      x_imag, xi_bf, x_real, xr_bf, (int)(n_x / 4));
  cvt2_kernel<<<dim3((int)(n_wp / 4 / 256)), blk, 0, stream>>>(
      Wq, Wq_bf, Wk, Wk_bf, (int)(n_wp / 4));
  cvt2_kernel<<<dim3((int)(n_w / 4 / 256)), blk, 0, stream>>>(
      Wv, Wv_bf, Wo, Wo_bf, (int)(n_w / 4));

  pgemm_kernel<<<dim3(M / 128, N_PHASE / 64, 2), blk, 0, stream>>>(
      xi_bf, Wq_bf, Wk_bf, bq, bk, qf, kf);
  mgemm_kernel<1><<<dim3(M / 128, D_MODEL / 64), blk, 0, stream>>>(
      xr_bf, Wv_bf, nullptr, Vt);
  attn_mfma_kernel<<<dim3(B_SZ * N_HEADS, L_SEQ / 64), blk, 0, stream>>>(
      qf, kf, Vt, ao_bf);
  mgemm_kernel<2><<<dim3(M / 128, D_MODEL / 64), blk, 0, stream>>>(
      ao_bf, Wo_bf, x_real, outr);
  ln_kernel<<<dim3(M), blk, 0, stream>>>(outr, gamma, beta);
  hipMemcpyAsync(outi, x_imag, sizeof(float) * n_x, hipMemcpyDeviceToDevice,
                 stream);
}

// Round 6
// 138.901 us; speedup vs baseline: 6.9287x; 1.1817x over previous
//
#include <hip/hip_runtime.h>
#include <math.h>

#define D_MODEL 1024
#define N_HEADS 16
#define N_PHASE 128
#define HEAD_DIM 64
#define B_SZ 2
#define L_SEQ 2048
#define QK_SCALE 0.35355339059327373f   // 1/sqrt(8)
#define LN_EPS 1e-5f
#define POS_COEF 0.07195578415606394f   // ln(10000)/128
#define INV_2PI 0.15915494309189535f

typedef __attribute__((ext_vector_type(8))) short bf16x8;
typedef __attribute__((ext_vector_type(4))) short s16x4;
typedef __attribute__((ext_vector_type(4))) float f32x4;

// ---------------------------------------------------------------- helpers
__device__ __forceinline__ float wave_reduce_sum(float v) {
#pragma unroll
  for (int off = 32; off > 0; off >>= 1) v += __shfl_xor(v, off);
  return v;
}
// f32 -> bf16 (RNE)
__device__ __forceinline__ unsigned short f2bf(float x) {
  unsigned u = __float_as_uint(x);
  u += 0x7fffu + ((u >> 16) & 1u);
  return (unsigned short)(u >> 16);
}
__device__ __forceinline__ void gload16(const short* g, short* l) {
  __builtin_amdgcn_global_load_lds(
      (const __attribute__((address_space(1))) void*)g,
      (__attribute__((address_space(3))) void*)l, 16, 0, 0);
}
// hw sin/cos with explicit range reduction (v_sin/v_cos take REVOLUTIONS,
// limited domain -> reduce to [-0.5, 0.5] rev with rndne first)
__device__ __forceinline__ void fast_sincos(float ang, float* s, float* c) {
  float rev = ang * INV_2PI;
  rev = rev - rintf(rev);
  *c = __builtin_amdgcn_cosf(rev);
  *s = __builtin_amdgcn_sinf(rev);
}

// ---------------------------------------------------------------- converts
// s0 -> d0 (bf16) and also copy s0 -> c0 (f32 passthrough); s1 -> d1 (bf16)
__global__ __launch_bounds__(256) void cvt2c_kernel(
    const float* __restrict__ s0, short* __restrict__ d0,
    float* __restrict__ c0, const float* __restrict__ s1,
    short* __restrict__ d1, int n4) {
  const int i = blockIdx.x * 256 + threadIdx.x;
  if (i < n4) {
    float4 v = ((const float4*)s0)[i];
    if (c0) ((float4*)c0)[i] = v;
    s16x4 o;
    o[0] = (short)f2bf(v.x);
    o[1] = (short)f2bf(v.y);
    o[2] = (short)f2bf(v.z);
    o[3] = (short)f2bf(v.w);
    ((s16x4*)d0)[i] = o;
    v = ((const float4*)s1)[i];
    o[0] = (short)f2bf(v.x);
    o[1] = (short)f2bf(v.y);
    o[2] = (short)f2bf(v.z);
    o[3] = (short)f2bf(v.w);
    ((s16x4*)d1)[i] = o;
  }
}

// ---------------------------------------------------------------- GEMM core
// 128x64 tile, BK=32, 4 waves (2x2). Wave tile 64x32, frags af[4] x bfr[2].
// LDS chunk-XOR swizzle (involution) applied on the GLOBAL source
// (gload_lds dest is linear) and on the LDS read side.
__device__ __forceinline__ void gemm_core(const short* __restrict__ A,
                                          const short* __restrict__ Bm, int K,
                                          int mBase, int nBase,
                                          f32x4 acc[4][2], short* As,
                                          short* Bs) {
  const int tid = threadIdx.x;
  const int wv = tid >> 6, ln = tid & 63;
  const int wr = wv >> 1, wc = wv & 1;
  const int fr = ln & 15, fc = ln >> 4;
  const int cg = (ln & 3) ^ ((ln >> 3) & 3);  // swizzled source chunk
  const short* ga = A + (size_t)(mBase + wv * 16 + (ln >> 2)) * K + cg * 8;
  const short* gb = Bm + (size_t)(nBase + wv * 16 + (ln >> 2)) * K + cg * 8;
  short* la = As + wv * 512;
  short* lb = Bs + wv * 512;
  const int ra = (wr * 64 + fr) * 32 + (fc ^ ((fr >> 1) & 3)) * 8;
  const int rb = (wc * 32 + fr) * 32 + (fc ^ ((fr >> 1) & 3)) * 8;

  for (int k0 = 0; k0 < K; k0 += 32) {
    __syncthreads();
    gload16(ga + k0, la);
    gload16(ga + k0 + (size_t)64 * K, la + 64 * 32);
    gload16(gb + k0, lb);
    __syncthreads();

    bf16x8 af[4], bfr[2];
#pragma unroll
    for (int mi = 0; mi < 4; ++mi) af[mi] = *(const bf16x8*)&As[ra + mi * 512];
#pragma unroll
    for (int ni = 0; ni < 2; ++ni) bfr[ni] = *(const bf16x8*)&Bs[rb + ni * 512];

#pragma unroll
    for (int mi = 0; mi < 4; ++mi)
#pragma unroll
      for (int ni = 0; ni < 2; ++ni)
        acc[mi][ni] = __builtin_amdgcn_mfma_f32_16x16x32_bf16(
            af[mi], bfr[ni], acc[mi][ni], 0, 0, 0);
  }
}

// ---------------------------------------------------------------- fused QKV projections
// grid (M/128, 20): y in [0,2) -> Q phase, [2,4) -> K phase, [4,20) -> V GEMM
__global__ __launch_bounds__(256) void qkv_kernel(
    const short* __restrict__ xi, const short* __restrict__ xr,
    const short* __restrict__ WqB, const short* __restrict__ WkB,
    const short* __restrict__ WvB, const float* __restrict__ bq,
    const float* __restrict__ bk, short* __restrict__ qf,
    short* __restrict__ kf, short* __restrict__ Vt) {
  __shared__ short As[128 * 32];
  __shared__ short Bs[64 * 32];
  const int y = blockIdx.y;
  const int mBase = blockIdx.x * 128;
  const short* A;
  const short* Bm;
  int nBase;
  if (y < 4) {
    A = xi;
    Bm = (y < 2) ? WqB : WkB;
    nBase = (y & 1) * 64;
  } else {
    A = xr;
    Bm = WvB;
    nBase = (y - 4) * 64;
  }

  f32x4 acc[4][2];
#pragma unroll
  for (int i = 0; i < 4; ++i)
#pragma unroll
    for (int j = 0; j < 2; ++j) acc[i][j] = (f32x4){0.f, 0.f, 0.f, 0.f};
  gemm_core(A, Bm, D_MODEL, mBase, nBase, acc, As, Bs);

  const int ln = threadIdx.x & 63, wv = threadIdx.x >> 6;
  const int wr = wv >> 1, wc = wv & 1;
  const int fr = ln & 15, fc = ln >> 4;

  if (y < 4) {
    const float* bias = (y < 2) ? bq : bk;
    short* Cs = (y < 2) ? qf : kf;
    const float fscale = (y < 2) ? QK_SCALE : 1.0f;
#pragma unroll
    for (int mi = 0; mi < 4; ++mi)
#pragma unroll
      for (int ni = 0; ni < 2; ++ni)
#pragma unroll
        for (int r = 0; r < 4; ++r) {
          const int m = mBase + wr * 64 + mi * 16 + fc * 4 + r;
          const int n = nBase + wc * 32 + ni * 16 + fr;
          const int b = m >> 11, l = m & (L_SEQ - 1);
          const float inv_freq = __expf(-(float)(n & ~1) * POS_COEF);
          const float ang = acc[mi][ni][r] + bias[n] + (float)l * inv_freq;
          float sv, cv;
          fast_sincos(ang, &sv, &cv);
          const int h = n >> 3, p = n & 7;
          const size_t base = ((size_t)((b << 4) + h) * L_SEQ + l) * 16;
          Cs[base + p] = (short)f2bf(cv * fscale);
          Cs[base + 8 + p] = (short)f2bf(sv * fscale);
        }
  } else {
    // Vt (B,H,64,L): n is the V-column (h,d); m is l -> 4 consecutive l's/lane
#pragma unroll
    for (int mi = 0; mi < 4; ++mi)
#pragma unroll
      for (int ni = 0; ni < 2; ++ni) {
        const int n = nBase + wc * 32 + ni * 16 + fr;
        const int m = mBase + wr * 64 + mi * 16 + fc * 4;
        const int b = m >> 11, l = m & (L_SEQ - 1);
        const int h = n >> 6, d = n & 63;
        s16x4 pk;
#pragma unroll
        for (int r = 0; r < 4; ++r) pk[r] = (short)f2bf(acc[mi][ni][r]);
        *(s16x4*)&Vt[((size_t)((b << 4) + h) * 64 + d) * L_SEQ + l] = pk;
      }
  }
}

// ---------------------------------------------------------------- O GEMM (+residual)
__global__ __launch_bounds__(256) void ogemm_kernel(
    const short* __restrict__ A, const short* __restrict__ Bm,
    const float* __restrict__ resid, float* __restrict__ Cf) {
  __shared__ short As[128 * 32];
  __shared__ short Bs[64 * 32];
  const int mBase = blockIdx.x * 128, nBase = blockIdx.y * 64;

  f32x4 acc[4][2];
#pragma unroll
  for (int i = 0; i < 4; ++i)
#pragma unroll
    for (int j = 0; j < 2; ++j) acc[i][j] = (f32x4){0.f, 0.f, 0.f, 0.f};
  gemm_core(A, Bm, D_MODEL, mBase, nBase, acc, As, Bs);

  const int ln = threadIdx.x & 63, wv = threadIdx.x >> 6;
  const int wr = wv >> 1, wc = wv & 1;
  const int fr = ln & 15, fc = ln >> 4;
#pragma unroll
  for (int mi = 0; mi < 4; ++mi)
#pragma unroll
    for (int ni = 0; ni < 2; ++ni)
#pragma unroll
      for (int r = 0; r < 4; ++r) {
        const int m = mBase + wr * 64 + mi * 16 + fc * 4 + r;
        const int n = nBase + wc * 32 + ni * 16 + fr;
        const size_t idx = (size_t)m * D_MODEL + n;
        Cf[idx] = acc[mi][ni][r] + resid[idx];
      }
}

// ---------------------------------------------------------------- MFMA attention
// grid (B*H, 16). Block handles q-tiles (31 - y) then (y): uniform 33 j-tiles.
// 4 waves, wave w owns 16 q rows of the 64-row q-tile.
// Scores bounded by 8*SCALE=2.83 -> exp directly, no online max.
__global__ __launch_bounds__(256) void attn_mfma_kernel(
    const short* __restrict__ qf, const short* __restrict__ kf,
    const short* __restrict__ Vt, short* __restrict__ ao) {
  const int bh = blockIdx.x;
  const int tid = threadIdx.x;
  const int w = tid >> 6;
  const int lane = tid & 63;
  const int g = lane >> 4;
  const int q16 = lane & 15;

  __shared__ short p_lds[4][16][72];

  const short* qf_h = qf + (size_t)bh * L_SEQ * 16;
  const short* kf_h = kf + (size_t)bh * L_SEQ * 16;
  const short* Vt_h = Vt + (size_t)bh * 64 * L_SEQ;
  const int b = bh >> 4, h = bh & 15;

#pragma unroll 1
  for (int half = 0; half < 2; ++half) {
    const int qtile = half ? blockIdx.y : (31 - blockIdx.y);
    const int qbase = qtile * 64;
    const int qglob = qbase + w * 16 + q16;
    const int ntiles = qtile + 1;

    bf16x8 qfrag = {0, 0, 0, 0, 0, 0, 0, 0};
    if (g < 2) qfrag = *(const bf16x8*)(qf_h + (size_t)qglob * 16 + g * 8);

    f32x4 o[4];
#pragma unroll
    for (int dc = 0; dc < 4; ++dc) o[dc] = (f32x4){0.f, 0.f, 0.f, 0.f};
    float lsum = 0.f;

    bf16x8 kfr[4], kfn[4];
#pragma unroll
    for (int jt = 0; jt < 4; ++jt) {
      kfr[jt] = (bf16x8){0, 0, 0, 0, 0, 0, 0, 0};
      kfn[jt] = (bf16x8){0, 0, 0, 0, 0, 0, 0, 0};
    }
    if (g < 2) {
#pragma unroll
      for (int jt = 0; jt < 4; ++jt)
        kfr[jt] = *(const bf16x8*)(kf_h + (size_t)(jt * 16 + q16) * 16 + g * 8);
    }

#pragma unroll 1
    for (int t = 0; t < ntiles; ++t) {
      const int j0 = t << 6;

      // V (c=0 half) for this tile
      bf16x8 vf0[4];
#pragma unroll
      for (int dc = 0; dc < 4; ++dc)
        vf0[dc] = *(const bf16x8*)(Vt_h + (size_t)(dc * 16 + q16) * L_SEQ + j0 +
                                   g * 8);
      // K for next tile
      if (t + 1 < ntiles && g < 2) {
#pragma unroll
        for (int jt = 0; jt < 4; ++jt)
          kfn[jt] = *(const bf16x8*)(kf_h +
                                     (size_t)(j0 + 64 + jt * 16 + q16) * 16 +
                                     g * 8);
      }

      // QK^T (swapped): lane holds q=q16, j = j0 + jt*16 + g*4 + r
      f32x4 s[4];
#pragma unroll
      for (int jt = 0; jt < 4; ++jt)
        s[jt] = __builtin_amdgcn_mfma_f32_16x16x32_bf16(
            kfr[jt], qfrag, (f32x4){0.f, 0.f, 0.f, 0.f}, 0, 0, 0);

      // V (c=1 half)
      bf16x8 vf1[4];
#pragma unroll
      for (int dc = 0; dc < 4; ++dc)
        vf1[dc] = *(const bf16x8*)(Vt_h + (size_t)(dc * 16 + q16) * L_SEQ + j0 +
                                   32 + g * 8);

      // causal mask (diagonal tile only)
      if (t == ntiles - 1) {
#pragma unroll
        for (int jt = 0; jt < 4; ++jt)
#pragma unroll
          for (int r = 0; r < 4; ++r)
            if (j0 + jt * 16 + g * 4 + r > qglob) s[jt][r] = -INFINITY;
      }

      // exp + per-lane sum + pack to LDS
#pragma unroll
      for (int jt = 0; jt < 4; ++jt) {
        const float e0 = __expf(s[jt][0]);
        const float e1 = __expf(s[jt][1]);
        const float e2 = __expf(s[jt][2]);
        const float e3 = __expf(s[jt][3]);
        lsum += (e0 + e1) + (e2 + e3);
        uint2 pk;
        pk.x = (unsigned)f2bf(e0) | ((unsigned)f2bf(e1) << 16);
        pk.y = (unsigned)f2bf(e2) | ((unsigned)f2bf(e3) << 16);
        *(uint2*)&p_lds[w][q16][jt * 16 + g * 4] = pk;
      }

      // PV: O^T += V^T @ P^T
      {
        const bf16x8 pb0 = *(const bf16x8*)&p_lds[w][q16][g * 8];
#pragma unroll
        for (int dc = 0; dc < 4; ++dc)
          o[dc] = __builtin_amdgcn_mfma_f32_16x16x32_bf16(vf0[dc], pb0, o[dc],
                                                          0, 0, 0);
        const bf16x8 pb1 = *(const bf16x8*)&p_lds[w][q16][32 + g * 8];
#pragma unroll
        for (int dc = 0; dc < 4; ++dc)
          o[dc] = __builtin_amdgcn_mfma_f32_16x16x32_bf16(vf1[dc], pb1, o[dc],
                                                          0, 0, 0);
      }

#pragma unroll
      for (int jt = 0; jt < 4; ++jt) kfr[jt] = kfn[jt];
    }

    lsum += __shfl_xor(lsum, 16);
    lsum += __shfl_xor(lsum, 32);
    const float inv = 1.f / lsum;
    short* orow = ao + ((size_t)(b * L_SEQ + qglob)) * D_MODEL + h * 64;
#pragma unroll
    for (int dc = 0; dc < 4; ++dc)
#pragma unroll
      for (int r = 0; r < 4; ++r)
        orow[dc * 16 + g * 4 + r] = (short)f2bf(o[dc][r] * inv);
  }
}

// ---------------------------------------------------------------- layernorm (in place)
__global__ __launch_bounds__(256) void ln_kernel(float* __restrict__ io,
                                                 const float* __restrict__ gamma,
                                                 const float* __restrict__ beta) {
  const int row = blockIdx.x;
  float* p = io + (size_t)row * D_MODEL;
  const int tid = threadIdx.x;
  float4 x = ((const float4*)p)[tid];
  float s = x.x + x.y + x.z + x.w;
  float sq = x.x * x.x + x.y * x.y + x.z * x.z + x.w * x.w;
  s = wave_reduce_sum(s);
  sq = wave_reduce_sum(sq);
  __shared__ float ss[4], ssq[4];
  const int w = tid >> 6, lane = tid & 63;
  if (lane == 0) {
    ss[w] = s;
    ssq[w] = sq;
  }
  __syncthreads();
  s = ss[0] + ss[1] + ss[2] + ss[3];
  sq = ssq[0] + ssq[1] + ssq[2] + ssq[3];
  const float mean = s * (1.f / D_MODEL);
  const float var = sq * (1.f / D_MODEL) - mean * mean;
  const float rstd = rsqrtf(var + LN_EPS);
  const float4 g = ((const float4*)gamma)[tid];
  const float4 bt = ((const float4*)beta)[tid];
  float4 y;
  y.x = (x.x - mean) * rstd * g.x + bt.x;
  y.y = (x.y - mean) * rstd * g.y + bt.y;
  y.z = (x.z - mean) * rstd * g.z + bt.z;
  y.w = (x.w - mean) * rstd * g.w + bt.w;
  ((float4*)p)[tid] = y;
}

// ---------------------------------------------------------------- launch
extern "C" void kernel_launch(void* const* d_in, const int* in_sizes, int n_in,
                              void* d_out, int out_size, void* d_ws,
                              size_t ws_size, hipStream_t stream) {
  const float* x_real = (const float*)d_in[0];
  const float* x_imag = (const float*)d_in[1];
  const float* Wq = (const float*)d_in[2];
  const float* bq = (const float*)d_in[3];
  const float* Wk = (const float*)d_in[4];
  const float* bk = (const float*)d_in[5];
  const float* Wv = (const float*)d_in[6];
  const float* Wo = (const float*)d_in[7];
  const float* gamma = (const float*)d_in[8];
  const float* beta = (const float*)d_in[9];

  const size_t n_x = (size_t)B_SZ * L_SEQ * D_MODEL;        // 4M
  const size_t n_w = (size_t)D_MODEL * D_MODEL;             // 1M
  const size_t n_wp = (size_t)N_PHASE * D_MODEL;            // 128K
  const size_t n_qf = (size_t)B_SZ * N_HEADS * L_SEQ * 16;  // 1M

  short* xi_bf = (short*)d_ws;
  short* xr_bf = xi_bf + n_x;  // later reused as ao_bf
  short* Wq_bf = xr_bf + n_x;
  short* Wk_bf = Wq_bf + n_wp;
  short* Wv_bf = Wk_bf + n_wp;
  short* Wo_bf = Wv_bf + n_w;
  short* qf = Wo_bf + n_w;
  short* kf = qf + n_qf;
  short* Vt = kf + n_qf;  // 4M shorts
  short* ao_bf = xr_bf;   // alias: x_real bf16 dead after V GEMM

  float* outr = (float*)d_out;
  float* outi = outr + n_x;

  const dim3 blk(256);
  const int M = B_SZ * L_SEQ;  // 4096

  cvt2c_kernel<<<dim3((int)(n_x / 4 / 256)), blk, 0, stream>>>(
      x_imag, xi_bf, outi, x_real, xr_bf, (int)(n_x / 4));
  cvt2c_kernel<<<dim3((int)(n_wp / 4 / 256)), blk, 0, stream>>>(
      Wq, Wq_bf, nullptr, Wk, Wk_bf, (int)(n_wp / 4));
  cvt2c_kernel<<<dim3((int)(n_w / 4 / 256)), blk, 0, stream>>>(
      Wv, Wv_bf, nullptr, Wo, Wo_bf, (int)(n_w / 4));

  qkv_kernel<<<dim3(M / 128, 20), blk, 0, stream>>>(
      xi_bf, xr_bf, Wq_bf, Wk_bf, Wv_bf, bq, bk, qf, kf, Vt);
  attn_mfma_kernel<<<dim3(B_SZ * N_HEADS, 16), blk, 0, stream>>>(qf, kf, Vt,
                                                                 ao_bf);
  ogemm_kernel<<<dim3(M / 128, D_MODEL / 64), blk, 0, stream>>>(
      ao_bf, Wo_bf, x_real, outr);
  ln_kernel<<<dim3(M), blk, 0, stream>>>(outr, gamma, beta);
}